// Round 4
// baseline (3126.541 us; speedup 1.0000x reference)
//
#include <hip/hip_runtime.h>
#include <hip/hip_bf16.h>

#define NUSERS 100000
#define NITEMS 50000
#define NN 150000            // total nodes
#define DD 64                // hidden dim
#define DE 16                // eigs dim
#define NLAYERS 2
#define NE 1500000           // edges per layer
#define NPATH 14
#define LN_EPS 1e-5f

// ---------------- init: x = concat(user_emb, item_emb) ----------------
__global__ void k_init(const float* __restrict__ uemb,
                       const float* __restrict__ iemb,
                       float* __restrict__ x) {
    int i = blockIdx.x * blockDim.x + threadIdx.x;
    if (i >= NN * DD) return;
    int row = i >> 6;
    x[i] = (row < NUSERS) ? uemb[i] : iemb[i - NUSERS * DD];
}

// ---------------- layernorm rows; also acc += x (for final mean) ------
__global__ void k_ln(const float* __restrict__ x,
                     float* __restrict__ acc,
                     float* __restrict__ y) {
    int row = blockIdx.x * 4 + (threadIdx.x >> 6);
    int lane = threadIdx.x & 63;
    if (row >= NN) return;
    int i = row * DD + lane;
    float v = x[i];
    acc[i] += v;
    float s = v;
    #pragma unroll
    for (int m = 32; m; m >>= 1) s += __shfl_xor(s, m, 64);
    float mu = s * (1.0f / 64.0f);
    float d = v - mu;
    float q = d * d;
    #pragma unroll
    for (int m = 32; m; m >>= 1) q += __shfl_xor(q, m, 64);
    float var = q * (1.0f / 64.0f);
    y[i] = d * rsqrtf(var + LN_EPS);
}

// ---------------- edge scores: e0 + atomic row sums -------------------
// 16 lanes per edge; lane j handles y elements [4j..4j+3] and eigs[j]
__global__ void k_edge(const float* __restrict__ y,
                       const float* __restrict__ eigs,
                       const int* __restrict__ rr, const int* __restrict__ cc,
                       const int* __restrict__ pt,
                       const float* __restrict__ pw,    // [L, NPATH]
                       const float* __restrict__ lam,   // [L]
                       int layer,
                       float* __restrict__ e0a,
                       float* __restrict__ rs0, float* __restrict__ rs1) {
    int e = blockIdx.x * 16 + (threadIdx.x >> 4);
    if (e >= NE) return;
    int lane = threadIdx.x & 15;
    int r = rr[e], c = cc[e];
    const float4* yr = reinterpret_cast<const float4*>(y + (size_t)r * DD);
    const float4* yc = reinterpret_cast<const float4*>(y + (size_t)c * DD);
    float4 a = yr[lane], b = yc[lane];
    float px = a.x * b.x + a.y * b.y + a.z * b.z + a.w * b.w;
    float pe = eigs[(size_t)r * DE + lane] * eigs[(size_t)c * DE + lane];
    #pragma unroll
    for (int m = 8; m; m >>= 1) {
        px += __shfl_xor(px, m, 16);
        pe += __shfl_xor(pe, m, 16);
    }
    if (lane == 0) {
        float elam = expf(lam[layer]);
        float v = px * 0.125f + elam * pe;
        float e0 = fminf(expf(v), 5.0f);
        float e1 = fminf(expf(pw[layer * NPATH + pt[e]]), 5.0f);
        e0a[e] = e0;
        atomicAdd(rs0 + r, e0);
        atomicAdd(rs1 + r, e1);
    }
}

// ---------------- reciprocal of row sums (handles s==0 -> 1) ----------
__global__ void k_recip(float* __restrict__ rs, int n) {
    int i = blockIdx.x * blockDim.x + threadIdx.x;
    if (i >= n) return;
    float v = rs[i];
    rs[i] = 1.0f / ((v == 0.0f) ? 1.0f : v);
}

// ---------------- SpMM scatter: x[r] += s * y[c] ----------------------
__global__ void k_spmm(const float* __restrict__ y,
                       const int* __restrict__ rr, const int* __restrict__ cc,
                       const int* __restrict__ pt,
                       const float* __restrict__ pw,
                       const float* __restrict__ e0a,
                       const float* __restrict__ rs0, const float* __restrict__ rs1,
                       int layer,
                       float* __restrict__ xo) {
    int e = blockIdx.x * 16 + (threadIdx.x >> 4);
    if (e >= NE) return;
    int lane = threadIdx.x & 15;
    int r = rr[e], c = cc[e];
    float e1 = fminf(expf(pw[layer * NPATH + pt[e]]), 5.0f);
    float s = 0.5f * (e0a[e] * rs0[r] + e1 * rs1[r]);
    const float4* yc = reinterpret_cast<const float4*>(y + (size_t)c * DD);
    float4 b = yc[lane];
    float* xr = xo + (size_t)r * DD + lane * 4;
    atomicAdd(xr + 0, s * b.x);
    atomicAdd(xr + 1, s * b.y);
    atomicAdd(xr + 2, s * b.z);
    atomicAdd(xr + 3, s * b.w);
}

// ---------------- final: out = (acc + x2) / 3 in f32 ------------------
__global__ void k_final(const float* __restrict__ acc,
                        const float* __restrict__ x,
                        float* __restrict__ out) {
    int i = blockIdx.x * blockDim.x + threadIdx.x;
    if (i >= NN * DD) return;
    out[i] = (acc[i] + x[i]) * (1.0f / 3.0f);
}

extern "C" void kernel_launch(void* const* d_in, const int* in_sizes, int n_in,
                              void* d_out, int out_size, void* d_ws, size_t ws_size,
                              hipStream_t stream) {
    const float* uemb = (const float*)d_in[0];
    const float* iemb = (const float*)d_in[1];
    const float* eigs = (const float*)d_in[2];
    const float* lam  = (const float*)d_in[3];
    const float* pw   = (const float*)d_in[4];
    const int* idx    = (const int*)d_in[5];   // [L, 2, E]
    const int* ptyp   = (const int*)d_in[6];   // [L, E]

    char* w = (char*)d_ws;
    float* acc = (float*)(w);                      // 38,400,000 B
    float* x   = (float*)(w + 38400000);           // 38,400,000 B
    float* y   = (float*)(w + 76800000);           // 38,400,000 B
    float* e0a = (float*)(w + 115200000);          //  6,000,000 B
    float* rs0 = (float*)(w + 121200000);          //    600,000 B
    float* rs1 = (float*)(w + 121800000);          //    600,000 B
    // total: 122,400,000 B

    const int nElem = NN * DD;                 // 9,600,000
    const int gElem = nElem / 256;             // 37,500
    const int gEdge = (NE + 15) / 16;          // 93,750
    const int gRows = (NN + 3) / 4;            // 37,500

    hipMemsetAsync(acc, 0, (size_t)nElem * 4, stream);
    k_init<<<gElem, 256, 0, stream>>>(uemb, iemb, x);

    for (int l = 0; l < NLAYERS; ++l) {
        k_ln<<<gRows, 256, 0, stream>>>(x, acc, y);
        hipMemsetAsync(x, 0, (size_t)nElem * 4, stream);
        hipMemsetAsync(rs0, 0, (size_t)NN * 4, stream);
        hipMemsetAsync(rs1, 0, (size_t)NN * 4, stream);
        const int* rr = idx + (size_t)l * 2 * NE;
        const int* cc = rr + NE;
        k_edge<<<gEdge, 256, 0, stream>>>(y, eigs, rr, cc, ptyp + (size_t)l * NE,
                                          pw, lam, l, e0a, rs0, rs1);
        k_recip<<<(NN + 127) / 128, 128, 0, stream>>>(rs0, NN);
        k_recip<<<(NN + 127) / 128, 128, 0, stream>>>(rs1, NN);
        k_spmm<<<gEdge, 256, 0, stream>>>(y, rr, cc, ptyp + (size_t)l * NE,
                                          pw, e0a, rs0, rs1, l, x);
    }
    k_final<<<gElem, 256, 0, stream>>>(acc, x, (float*)d_out);
}

// Round 5
// 1090.186 us; speedup vs baseline: 2.8679x; 2.8679x over previous
//
#include <hip/hip_runtime.h>
#include <hip/hip_bf16.h>

#define NUSERS 100000
#define NITEMS 50000
#define NN 150000            // total nodes
#define DD 64                // hidden dim
#define DE 16                // eigs dim
#define NLAYERS 2
#define NE 1500000           // edges per layer
#define NPATH 14
#define LN_EPS 1e-5f
#define SCAN_BLK 1024
#define NSCAN ((NN + SCAN_BLK - 1) / SCAN_BLK)   // 147

// bf16 bits -> f32
__device__ __forceinline__ float b2f(unsigned int h) {
    union { unsigned int u; float f; } v;
    v.u = h << 16;
    return v.f;
}

// ---------------- init: x = concat(user_emb, item_emb) ----------------
__global__ void k_init(const float* __restrict__ uemb,
                       const float* __restrict__ iemb,
                       float* __restrict__ x) {
    int i = blockIdx.x * blockDim.x + threadIdx.x;
    if (i >= NN * DD) return;
    int row = i >> 6;
    x[i] = (row < NUSERS) ? uemb[i] : iemb[i - NUSERS * DD];
}

// ------- layernorm rows -> y (bf16); also acc += x (final mean) -------
__global__ void k_ln(const float* __restrict__ x,
                     float* __restrict__ acc,
                     unsigned short* __restrict__ y) {
    int row = blockIdx.x * 4 + (threadIdx.x >> 6);
    int lane = threadIdx.x & 63;
    if (row >= NN) return;
    int i = row * DD + lane;
    float v = x[i];
    acc[i] += v;
    float s = v;
    #pragma unroll
    for (int m = 32; m; m >>= 1) s += __shfl_xor(s, m, 64);
    float mu = s * (1.0f / 64.0f);
    float d = v - mu;
    float q = d * d;
    #pragma unroll
    for (int m = 32; m; m >>= 1) q += __shfl_xor(q, m, 64);
    float var = q * (1.0f / 64.0f);
    float yn = d * rsqrtf(var + LN_EPS);
    __hip_bfloat16 h = __float2bfloat16(yn);
    y[i] = *reinterpret_cast<unsigned short*>(&h);
}

// ---------------- degree histogram into cursor ------------------------
__global__ void k_hist(const int* __restrict__ rr, int* __restrict__ cnt) {
    int e = blockIdx.x * blockDim.x + threadIdx.x;
    if (e < NE) atomicAdd(cnt + rr[e], 1);
}

// ---------------- scan pass 1: per-block exclusive scan ---------------
__global__ void k_scan1(const int* __restrict__ cnt,
                        int* __restrict__ off, int* __restrict__ bsum) {
    __shared__ int sm[SCAN_BLK];
    int t = threadIdx.x;
    int i = blockIdx.x * SCAN_BLK + t;
    int v = (i < NN) ? cnt[i] : 0;
    sm[t] = v;
    __syncthreads();
    #pragma unroll
    for (int d = 1; d < SCAN_BLK; d <<= 1) {
        int a = (t >= d) ? sm[t - d] : 0;
        __syncthreads();
        sm[t] += a;
        __syncthreads();
    }
    if (i < NN) off[i] = sm[t] - v;          // exclusive, partial
    if (t == SCAN_BLK - 1) bsum[blockIdx.x] = sm[t];
}

// ---------------- scan pass 2: scan the block sums (in place) ---------
__global__ void k_scan2(int* __restrict__ bsum) {
    __shared__ int sm[256];
    int t = threadIdx.x;
    int v = (t < NSCAN) ? bsum[t] : 0;
    sm[t] = v;
    __syncthreads();
    #pragma unroll
    for (int d = 1; d < 256; d <<= 1) {
        int a = (t >= d) ? sm[t - d] : 0;
        __syncthreads();
        sm[t] += a;
        __syncthreads();
    }
    if (t < NSCAN) bsum[t] = sm[t] - v;      // exclusive
}

// ---------------- scan pass 3: add block offset; cursor = off ---------
__global__ void k_scan3(int* __restrict__ off, const int* __restrict__ bsum,
                        int* __restrict__ cursor) {
    int i = blockIdx.x * SCAN_BLK + threadIdx.x;
    if (i == 0) off[NN] = NE;
    if (i >= NN) return;
    int v = off[i] + bsum[blockIdx.x];
    off[i] = v;
    cursor[i] = v;
}

// ---------------- edge scores: e0 + atomic row sums -------------------
// 16 lanes per edge; lane j handles y elems [4j..4j+3] and eigs[j]
__global__ void k_edge(const unsigned short* __restrict__ y,
                       const float* __restrict__ eigs,
                       const int* __restrict__ rr, const int* __restrict__ cc,
                       const int* __restrict__ pt,
                       const float* __restrict__ pw,    // [L, NPATH]
                       const float* __restrict__ lam,   // [L]
                       int layer,
                       float* __restrict__ e0a,
                       float* __restrict__ rs0, float* __restrict__ rs1) {
    int e = blockIdx.x * 16 + (threadIdx.x >> 4);
    if (e >= NE) return;
    int lane = threadIdx.x & 15;
    int r = rr[e], c = cc[e];
    const uint2* yr = reinterpret_cast<const uint2*>(y + (size_t)r * DD);
    const uint2* yc = reinterpret_cast<const uint2*>(y + (size_t)c * DD);
    uint2 a = yr[lane], b = yc[lane];
    float px = b2f(a.x & 0xffffu) * b2f(b.x & 0xffffu)
             + b2f(a.x >> 16)     * b2f(b.x >> 16)
             + b2f(a.y & 0xffffu) * b2f(b.y & 0xffffu)
             + b2f(a.y >> 16)     * b2f(b.y >> 16);
    float pe = eigs[(size_t)r * DE + lane] * eigs[(size_t)c * DE + lane];
    #pragma unroll
    for (int m = 8; m; m >>= 1) {
        px += __shfl_xor(px, m, 16);
        pe += __shfl_xor(pe, m, 16);
    }
    if (lane == 0) {
        float elam = expf(lam[layer]);
        float v = px * 0.125f + elam * pe;
        float e0 = fminf(expf(v), 5.0f);
        float e1 = fminf(expf(pw[layer * NPATH + pt[e]]), 5.0f);
        e0a[e] = e0;
        atomicAdd(rs0 + r, e0);
        atomicAdd(rs1 + r, e1);
    }
}

// ---------------- reciprocal of row sums (s==0 -> 1) ------------------
__global__ void k_recip(float* __restrict__ rs, int n) {
    int i = blockIdx.x * blockDim.x + threadIdx.x;
    if (i >= n) return;
    float v = rs[i];
    rs[i] = 1.0f / ((v == 0.0f) ? 1.0f : v);
}

// ------- fill CSR with (col, s) pairs; s = final edge coefficient -----
__global__ void k_fillsval(const int* __restrict__ rr, const int* __restrict__ cc,
                           const int* __restrict__ pt,
                           const float* __restrict__ pw,
                           const float* __restrict__ e0a,
                           const float* __restrict__ rs0, const float* __restrict__ rs1,
                           int layer,
                           int* __restrict__ cursor, int2* __restrict__ csv) {
    int e = blockIdx.x * blockDim.x + threadIdx.x;
    if (e >= NE) return;
    int r = rr[e];
    float e1 = fminf(expf(pw[layer * NPATH + pt[e]]), 5.0f);
    float s = 0.5f * (e0a[e] * rs0[r] + e1 * rs1[r]);
    int pos = atomicAdd(cursor + r, 1);
    csv[pos] = make_int2(cc[e], __float_as_int(s));
}

// ---------------- SpMM gather: x[r] = sum_e s_e * y[c_e] --------------
// one 64-lane wave per row, lane = dim
__global__ void k_spmm_csr(const unsigned short* __restrict__ y,
                           const int* __restrict__ off,
                           const int2* __restrict__ csv,
                           float* __restrict__ x) {
    int row = blockIdx.x * 4 + (threadIdx.x >> 6);
    int lane = threadIdx.x & 63;
    if (row >= NN) return;
    int p0 = off[row], p1 = off[row + 1];
    float acc = 0.0f;
    for (int p = p0; p < p1; ++p) {
        int2 cs = csv[p];                     // wave-uniform broadcast
        float s = __int_as_float(cs.y);
        acc += s * b2f(y[(size_t)cs.x * DD + lane]);
    }
    x[(size_t)row * DD + lane] = acc;
}

// ---------------- final: out = (acc + x2) / 3 in f32 ------------------
__global__ void k_final(const float* __restrict__ acc,
                        const float* __restrict__ x,
                        float* __restrict__ out) {
    int i = blockIdx.x * blockDim.x + threadIdx.x;
    if (i >= NN * DD) return;
    out[i] = (acc[i] + x[i]) * (1.0f / 3.0f);
}

extern "C" void kernel_launch(void* const* d_in, const int* in_sizes, int n_in,
                              void* d_out, int out_size, void* d_ws, size_t ws_size,
                              hipStream_t stream) {
    const float* uemb = (const float*)d_in[0];
    const float* iemb = (const float*)d_in[1];
    const float* eigs = (const float*)d_in[2];
    const float* lam  = (const float*)d_in[3];
    const float* pw   = (const float*)d_in[4];
    const int* idx    = (const int*)d_in[5];   // [L, 2, E]
    const int* ptyp   = (const int*)d_in[6];   // [L, E]

    char* w = (char*)d_ws;
    float*          acc    = (float*)(w);                        // 38,400,000
    float*          x      = (float*)(w + 38400000);             // 38,400,000
    float*          e0a    = (float*)(w + 38400000);             // overlays x (dead mid-layer)
    unsigned short* y      = (unsigned short*)(w + 76800000);    // 19,200,000
    int2*           csv    = (int2*)(w + 96000000);              // 12,000,000
    int*            off    = (int*)(w + 108000000);              //    600,004
    int*            cursor = (int*)(w + 108600032);              //    600,000
    float*          rs0    = (float*)(w + 109200032);            //    600,000
    float*          rs1    = (float*)(w + 109800032);            //    600,000 (contiguous after rs0)
    int*            bsum   = (int*)(w + 110400032);              //        588
    // total ~110.4 MB

    const int nElem = NN * DD;                 // 9,600,000
    const int gElem = nElem / 256;             // 37,500
    const int gEdge16 = (NE + 15) / 16;        // 93,750  (16 lanes/edge)
    const int gEdge1  = (NE + 255) / 256;      // 5,860   (1 thread/edge)
    const int gRows = NN / 4;                  // 37,500

    hipMemsetAsync(acc, 0, (size_t)nElem * 4, stream);
    k_init<<<gElem, 256, 0, stream>>>(uemb, iemb, x);

    for (int l = 0; l < NLAYERS; ++l) {
        const int* rr = idx + (size_t)l * 2 * NE;
        const int* cc = rr + NE;
        const int* pt = ptyp + (size_t)l * NE;

        k_ln<<<gRows, 256, 0, stream>>>(x, acc, y);
        // zero cursor + rs0 + rs1 in one contiguous memset
        hipMemsetAsync(cursor, 0, 1800000, stream);
        // CSR build
        k_hist<<<gEdge1, 256, 0, stream>>>(rr, cursor);
        k_scan1<<<NSCAN, SCAN_BLK, 0, stream>>>(cursor, off, bsum);
        k_scan2<<<1, 256, 0, stream>>>(bsum);
        k_scan3<<<NSCAN, SCAN_BLK, 0, stream>>>(off, bsum, cursor);
        // edge scores + row sums
        k_edge<<<gEdge16, 256, 0, stream>>>(y, eigs, rr, cc, pt, pw, lam, l,
                                            e0a, rs0, rs1);
        k_recip<<<(2 * NN + 255) / 256, 256, 0, stream>>>(rs0, 2 * NN);  // rs0+rs1
        // scatter (col, s) into CSR order
        k_fillsval<<<gEdge1, 256, 0, stream>>>(rr, cc, pt, pw, e0a, rs0, rs1, l,
                                               cursor, csv);
        // gather SpMM, no atomics
        k_spmm_csr<<<gRows, 256, 0, stream>>>(y, off, csv, x);
    }
    k_final<<<gElem, 256, 0, stream>>>(acc, x, (float*)d_out);
}

// Round 6
// 704.620 us; speedup vs baseline: 4.4372x; 1.5472x over previous
//
#include <hip/hip_runtime.h>
#include <hip/hip_bf16.h>

#define NUSERS 100000
#define NITEMS 50000
#define NN 150000            // total nodes
#define DD 64                // hidden dim
#define DE 16                // eigs dim
#define NLAYERS 2
#define NE 1500000           // edges per layer
#define NPATH 14
#define LN_EPS 1e-5f
#define SCAN_BLK 1024
#define NSCAN ((NN + SCAN_BLK - 1) / SCAN_BLK)   // 147

// bf16 bits -> f32
__device__ __forceinline__ float b2f(unsigned int h) {
    union { unsigned int u; float f; } v;
    v.u = h << 16;
    return v.f;
}

// ---------------- init: x = concat(user_emb, item_emb) ----------------
__global__ void k_init(const float* __restrict__ uemb,
                       const float* __restrict__ iemb,
                       float* __restrict__ x) {
    int i = blockIdx.x * blockDim.x + threadIdx.x;
    if (i >= NN * DD) return;
    int row = i >> 6;
    x[i] = (row < NUSERS) ? uemb[i] : iemb[i - NUSERS * DD];
}

// ------- layernorm rows -> y (bf16); also acc += x (final mean) -------
__global__ void k_ln(const float* __restrict__ x,
                     float* __restrict__ acc,
                     unsigned short* __restrict__ y) {
    int row = blockIdx.x * 4 + (threadIdx.x >> 6);
    int lane = threadIdx.x & 63;
    if (row >= NN) return;
    int i = row * DD + lane;
    float v = x[i];
    acc[i] += v;
    float s = v;
    #pragma unroll
    for (int m = 32; m; m >>= 1) s += __shfl_xor(s, m, 64);
    float mu = s * (1.0f / 64.0f);
    float d = v - mu;
    float q = d * d;
    #pragma unroll
    for (int m = 32; m; m >>= 1) q += __shfl_xor(q, m, 64);
    float var = q * (1.0f / 64.0f);
    float yn = d * rsqrtf(var + LN_EPS);
    __hip_bfloat16 h = __float2bfloat16(yn);
    y[i] = *reinterpret_cast<unsigned short*>(&h);
}

// ---------------- degree histogram into cursor ------------------------
__global__ void k_hist(const int* __restrict__ rr, int* __restrict__ cnt) {
    int e = blockIdx.x * blockDim.x + threadIdx.x;
    if (e < NE) atomicAdd(cnt + rr[e], 1);
}

// ---------------- scan pass 1: per-block exclusive scan ---------------
__global__ void k_scan1(const int* __restrict__ cnt,
                        int* __restrict__ off, int* __restrict__ bsum) {
    __shared__ int sm[SCAN_BLK];
    int t = threadIdx.x;
    int i = blockIdx.x * SCAN_BLK + t;
    int v = (i < NN) ? cnt[i] : 0;
    sm[t] = v;
    __syncthreads();
    #pragma unroll
    for (int d = 1; d < SCAN_BLK; d <<= 1) {
        int a = (t >= d) ? sm[t - d] : 0;
        __syncthreads();
        sm[t] += a;
        __syncthreads();
    }
    if (i < NN) off[i] = sm[t] - v;          // exclusive, partial
    if (t == SCAN_BLK - 1) bsum[blockIdx.x] = sm[t];
}

// ---------------- scan pass 2: scan the block sums (in place) ---------
__global__ void k_scan2(int* __restrict__ bsum) {
    __shared__ int sm[256];
    int t = threadIdx.x;
    int v = (t < NSCAN) ? bsum[t] : 0;
    sm[t] = v;
    __syncthreads();
    #pragma unroll
    for (int d = 1; d < 256; d <<= 1) {
        int a = (t >= d) ? sm[t - d] : 0;
        __syncthreads();
        sm[t] += a;
        __syncthreads();
    }
    if (t < NSCAN) bsum[t] = sm[t] - v;      // exclusive
}

// ---------------- scan pass 3: add block offset; cursor = off ---------
__global__ void k_scan3(int* __restrict__ off, const int* __restrict__ bsum,
                        int* __restrict__ cursor) {
    int i = blockIdx.x * SCAN_BLK + threadIdx.x;
    if (i == 0) off[NN] = NE;
    if (i >= NN) return;
    int v = off[i] + bsum[blockIdx.x];
    off[i] = v;
    cursor[i] = v;
}

// ------- fill CSR: packed (col | pt<<18) per edge in row order --------
__global__ void k_fill(const int* __restrict__ rr, const int* __restrict__ cc,
                       const int* __restrict__ pt,
                       int* __restrict__ cursor, int* __restrict__ csv) {
    int e = blockIdx.x * blockDim.x + threadIdx.x;
    if (e >= NE) return;
    int pos = atomicAdd(cursor + rr[e], 1);
    csv[pos] = cc[e] | (pt[e] << 18);        // col < 2^18, pt < 14
}

// ---- fused per-row: scores + dual softmax sums + SpMM, single pass ---
// x[r] = 0.5*rinv0*sum(e0*y[c]) + 0.5*rinv1*sum(e1*y[c])
// wave per row; 4 edge-slots (groups of 16 lanes); lane sl covers dims 4sl..4sl+3
__global__ void k_row(const unsigned short* __restrict__ y,
                      const float* __restrict__ eigs,
                      const int* __restrict__ off,
                      const int* __restrict__ csv,
                      const float* __restrict__ pw,   // [L, NPATH]
                      const float* __restrict__ lam,  // [L]
                      int layer,
                      float* __restrict__ x) {
    __shared__ float pexp[NPATH];
    __shared__ float selam;
    int t = threadIdx.x;
    if (t < NPATH) pexp[t] = fminf(expf(pw[layer * NPATH + t]), 5.0f);
    if (t == NPATH) selam = expf(lam[layer]);
    __syncthreads();

    int row = blockIdx.x * 4 + (t >> 6);     // NN % 4 == 0, always valid
    int lane = t & 63;
    int g = lane >> 4;                        // edge slot 0..3
    int sl = lane & 15;                       // sub-lane (dim group)
    int p0 = off[row], p1 = off[row + 1];

    const uint2* yrp = reinterpret_cast<const uint2*>(y + (size_t)row * DD);
    uint2 ar = yrp[sl];
    float ax = b2f(ar.x & 0xffffu), ay = b2f(ar.x >> 16);
    float az = b2f(ar.y & 0xffffu), aw = b2f(ar.y >> 16);
    float er = eigs[(size_t)row * DE + sl];
    float elam = selam;

    float sum0 = 0.f, sum1 = 0.f;
    float4 A = make_float4(0.f, 0.f, 0.f, 0.f);
    float4 B = make_float4(0.f, 0.f, 0.f, 0.f);

    for (int p = p0; p < p1; p += 4) {
        int pe_ = p + g;
        bool ok = pe_ < p1;
        int cv = 0;
        uint2 b = make_uint2(0u, 0u);
        float ec = 0.f;
        if (ok) {
            cv = csv[pe_];
            int c = cv & 0x3ffff;
            b = reinterpret_cast<const uint2*>(y + (size_t)c * DD)[sl];
            ec = eigs[(size_t)c * DE + sl];
        }
        float bx = b2f(b.x & 0xffffu), by = b2f(b.x >> 16);
        float bz = b2f(b.y & 0xffffu), bw = b2f(b.y >> 16);
        float px = ax * bx + ay * by + az * bz + aw * bw;
        float pe = er * ec;
        #pragma unroll
        for (int m = 8; m; m >>= 1) {
            px += __shfl_xor(px, m, 64);     // reduce within 16-lane group
            pe += __shfl_xor(pe, m, 64);
        }
        float v = px * 0.125f + elam * pe;
        float e0 = ok ? fminf(expf(v), 5.0f) : 0.f;
        float e1 = ok ? pexp[(unsigned)cv >> 18] : 0.f;
        sum0 += e0;
        sum1 += e1;
        A.x += e0 * bx; A.y += e0 * by; A.z += e0 * bz; A.w += e0 * bw;
        B.x += e1 * bx; B.y += e1 * by; B.z += e1 * bz; B.w += e1 * bw;
    }

    // total row sums across the 4 groups
    #pragma unroll
    for (int m = 16; m <= 32; m <<= 1) {
        sum0 += __shfl_xor(sum0, m, 64);
        sum1 += __shfl_xor(sum1, m, 64);
    }
    float rinv0 = 0.5f / ((sum0 == 0.f) ? 1.f : sum0);
    float rinv1 = 0.5f / ((sum1 == 0.f) ? 1.f : sum1);

    float4 acc4;
    acc4.x = rinv0 * A.x + rinv1 * B.x;
    acc4.y = rinv0 * A.y + rinv1 * B.y;
    acc4.z = rinv0 * A.z + rinv1 * B.z;
    acc4.w = rinv0 * A.w + rinv1 * B.w;
    // each 16-lane group holds a full 64-dim partial; reduce across groups
    #pragma unroll
    for (int m = 16; m <= 32; m <<= 1) {
        acc4.x += __shfl_xor(acc4.x, m, 64);
        acc4.y += __shfl_xor(acc4.y, m, 64);
        acc4.z += __shfl_xor(acc4.z, m, 64);
        acc4.w += __shfl_xor(acc4.w, m, 64);
    }
    if (g == 0) {
        reinterpret_cast<float4*>(x + (size_t)row * DD)[sl] = acc4;
    }
}

// ---------------- final: out = (acc + x2) / 3 in f32 ------------------
__global__ void k_final(const float* __restrict__ acc,
                        const float* __restrict__ x,
                        float* __restrict__ out) {
    int i = blockIdx.x * blockDim.x + threadIdx.x;
    if (i >= NN * DD) return;
    out[i] = (acc[i] + x[i]) * (1.0f / 3.0f);
}

extern "C" void kernel_launch(void* const* d_in, const int* in_sizes, int n_in,
                              void* d_out, int out_size, void* d_ws, size_t ws_size,
                              hipStream_t stream) {
    const float* uemb = (const float*)d_in[0];
    const float* iemb = (const float*)d_in[1];
    const float* eigs = (const float*)d_in[2];
    const float* lam  = (const float*)d_in[3];
    const float* pw   = (const float*)d_in[4];
    const int* idx    = (const int*)d_in[5];   // [L, 2, E]
    const int* ptyp   = (const int*)d_in[6];   // [L, E]

    char* w = (char*)d_ws;
    float*          acc    = (float*)(w);                        // 38,400,000
    float*          x      = (float*)(w + 38400000);             // 38,400,000
    unsigned short* y      = (unsigned short*)(w + 76800000);    // 19,200,000
    int*            csv    = (int*)(w + 96000000);               //  6,000,000
    int*            off    = (int*)(w + 102000000);              //    600,004
    int*            cursor = (int*)(w + 102600032);              //    600,000
    int*            bsum   = (int*)(w + 103200032);              //        588
    // total ~103.2 MB

    const int nElem = NN * DD;                 // 9,600,000
    const int gElem = nElem / 256;             // 37,500
    const int gEdge1 = (NE + 255) / 256;       // 5,860
    const int gRows = NN / 4;                  // 37,500

    hipMemsetAsync(acc, 0, (size_t)nElem * 4, stream);
    k_init<<<gElem, 256, 0, stream>>>(uemb, iemb, x);

    for (int l = 0; l < NLAYERS; ++l) {
        const int* rr = idx + (size_t)l * 2 * NE;
        const int* cc = rr + NE;
        const int* pt = ptyp + (size_t)l * NE;

        k_ln<<<gRows, 256, 0, stream>>>(x, acc, y);
        hipMemsetAsync(cursor, 0, (size_t)NN * 4, stream);
        k_hist<<<gEdge1, 256, 0, stream>>>(rr, cursor);
        k_scan1<<<NSCAN, SCAN_BLK, 0, stream>>>(cursor, off, bsum);
        k_scan2<<<1, 256, 0, stream>>>(bsum);
        k_scan3<<<NSCAN, SCAN_BLK, 0, stream>>>(off, bsum, cursor);
        k_fill<<<gEdge1, 256, 0, stream>>>(rr, cc, pt, cursor, csv);
        k_row<<<gRows, 256, 0, stream>>>(y, eigs, off, csv, pw, lam, l, x);
    }
    k_final<<<gElem, 256, 0, stream>>>(acc, x, (float*)d_out);
}